// Round 12
// baseline (135.303 us; speedup 1.0000x reference)
//
#include <hip/hip_runtime.h>
#include <stdint.h>

#define D 4096
#define RANK 8
#define ALPHA 1.5f
#define BETA 0.5f
#define SUM_TIMESTEPS 28000
#define K_TOP 64
#define NBINS 1024

typedef float f32x4 __attribute__((ext_vector_type(4)));

// ws layout (bytes):
//   [0, 256)            : u32 hdr[]: [4]=flag (written unconditionally each call)
//   [256, 256+8K)       : u32 gcnt[2][NBINS]   (zeroed by k_pass_max each call)
//   [8448, 8448+16K)    : u64 gsum[2][NBINS]   (zeroed by k_pass_max each call)
//   [24832, 24832+2K)   : u32 bmax[2][256]     (written unconditionally each call)
//   [26880, +4M)        : f32 part[65536][16]  (t partials; fully written each call)
#define WS_GCNT_OFF 256
#define WS_GSUM_OFF (256 + 2 * NBINS * 4)
#define WS_BMAX_OFF (WS_GSUM_OFF + 2 * NBINS * 8)
#define WS_PART_OFF (WS_BMAX_OFF + 2048)

// fixed-point scale: 2^38 / max  (sum of 16.7M maximal values still < 2^62)
#define FIX_NUM 2.74877906944e11f
#define FIX_INV 3.637978807091713e-12   // 2^-38

__device__ __forceinline__ float dot4v(f32x4 a, f32x4 b) {
    return fmaf(a.x, b.x, fmaf(a.y, b.y, fmaf(a.z, b.z, a.w * b.w)));
}

// ---------------------------------------------------------------------------
// Pass 1: per-block max of |wa@wb| -> bmax[mat][bid]. wa slice staged in LDS.
// Zeroes gcnt/gsum for the NEXT kernel. grid (256, 2), block 256.
// ---------------------------------------------------------------------------
__global__ __launch_bounds__(256) void k_pass_max(
    const float* __restrict__ wa1, const float* __restrict__ wb1,
    const float* __restrict__ wa2, const float* __restrict__ wb2,
    unsigned* __restrict__ gz, unsigned* __restrict__ bmax) {
    const int tid = threadIdx.x;
    const int mat = blockIdx.y;
    const int bid = blockIdx.x;
    // zero gcnt/gsum stripes (consumed by the NEXT kernel, so no race)
    if (mat == 0 && tid < 24) gz[bid * 24 + tid] = 0u;

    const float* __restrict__ wa = mat ? wa2 : wa1;
    const float* __restrict__ wb = mat ? wb2 : wb1;
    const int i0 = (bid & 3) * 1024 + tid * 4;
    const int obase = (bid >> 2) * 64;

    __shared__ float was[64][8];  // 2 KB wa slice
    if (tid < 128)
        ((f32x4*)was)[tid] = ((const f32x4*)(wa + (size_t)obase * RANK))[tid];

    f32x4 wbv[RANK];
#pragma unroll
    for (int r = 0; r < RANK; ++r)
        wbv[r] = *(const f32x4*)(wb + r * D + i0);
    __syncthreads();

    float vmax = 0.f;
#pragma unroll 4
    for (int oo = 0; oo < 64; ++oo) {
        const f32x4 w03 = *(const f32x4*)&was[oo][0];  // LDS broadcast
        const f32x4 w47 = *(const f32x4*)&was[oo][4];
        f32x4 s = {0.f, 0.f, 0.f, 0.f};
        const float a[8] = {w03.x, w03.y, w03.z, w03.w, w47.x, w47.y, w47.z, w47.w};
#pragma unroll
        for (int r = 0; r < RANK; ++r) {
            s.x = fmaf(a[r], wbv[r].x, s.x);
            s.y = fmaf(a[r], wbv[r].y, s.y);
            s.z = fmaf(a[r], wbv[r].z, s.z);
            s.w = fmaf(a[r], wbv[r].w, s.w);
        }
        vmax = fmaxf(vmax, fmaxf(fmaxf(fabsf(s.x), fabsf(s.y)),
                                 fmaxf(fabsf(s.z), fabsf(s.w))));
    }
    for (int off = 32; off; off >>= 1)
        vmax = fmaxf(vmax, __shfl_xor(vmax, off, 64));
    __shared__ float smax[4];
    const int wave = tid >> 6, lane = tid & 63;
    if (lane == 0) smax[wave] = vmax;
    __syncthreads();
    if (tid == 0) {
        float m = fmaxf(fmaxf(smax[0], smax[1]), fmaxf(smax[2], smax[3]));
        bmax[mat * 256 + bid] = __float_as_uint(m);  // unconditional write
    }
}

// ---------------------------------------------------------------------------
// helper: block-level max over 256 bmax entries (block must be >=256 thr)
// ---------------------------------------------------------------------------
__device__ __forceinline__ float block_max256(const unsigned* __restrict__ bmax,
                                              int mat, int tid, float* redm) {
    const int wave = tid >> 6, lane = tid & 63;
    float m = 0.f;
    if (tid < 256) m = __uint_as_float(bmax[mat * 256 + tid]);
    for (int off = 32; off; off >>= 1)
        m = fmaxf(m, __shfl_xor(m, off, 64));
    if (tid < 256 && lane == 0) redm[wave] = m;
    __syncthreads();
    return fmaxf(fmaxf(redm[0], redm[1]), fmaxf(redm[2], redm[3]));
}

// ---------------------------------------------------------------------------
// Pass 2: histogram all |elem| >= 0.5*max. Counts u32, sums u64 fixed-point
// (order-independent integer atomics -> bit-deterministic across replays).
// wa slice staged in LDS. grid (256, 2), block 256.
// ---------------------------------------------------------------------------
__global__ __launch_bounds__(256) void k_pass_hist(
    const float* __restrict__ wa1, const float* __restrict__ wb1,
    const float* __restrict__ wa2, const float* __restrict__ wb2,
    const unsigned* __restrict__ bmax,
    unsigned* __restrict__ gcnt, unsigned long long* __restrict__ gsum) {
    __shared__ unsigned lcnt[NBINS];
    __shared__ unsigned long long lsum[NBINS];
    __shared__ float was[64][8];
    __shared__ float redm[4];
    const int tid = threadIdx.x;
    const int mat = blockIdx.y;
    for (int b = tid; b < NBINS; b += 256) { lcnt[b] = 0u; lsum[b] = 0ull; }

    const float* __restrict__ wa = mat ? wa2 : wa1;
    const float* __restrict__ wb = mat ? wb2 : wb1;
    const int i0 = (blockIdx.x & 3) * 1024 + tid * 4;
    const int obase = (blockIdx.x >> 2) * 64;
    if (tid < 128)
        ((f32x4*)was)[tid] = ((const f32x4*)(wa + (size_t)obase * RANK))[tid];

    // (block_max256 contains the needed barrier)
    const float M = block_max256(bmax, mat, tid, redm);
    const float T = 0.5f * M;
    const float fix = FIX_NUM / M;
    const unsigned bitsT = __float_as_uint(T);

    f32x4 wbv[RANK];
#pragma unroll
    for (int r = 0; r < RANK; ++r)
        wbv[r] = *(const f32x4*)(wb + r * D + i0);

#pragma unroll 2
    for (int oo = 0; oo < 64; ++oo) {
        const f32x4 w03 = *(const f32x4*)&was[oo][0];
        const f32x4 w47 = *(const f32x4*)&was[oo][4];
        f32x4 s = {0.f, 0.f, 0.f, 0.f};
        const float a[8] = {w03.x, w03.y, w03.z, w03.w, w47.x, w47.y, w47.z, w47.w};
#pragma unroll
        for (int r = 0; r < RANK; ++r) {
            s.x = fmaf(a[r], wbv[r].x, s.x);
            s.y = fmaf(a[r], wbv[r].y, s.y);
            s.z = fmaf(a[r], wbv[r].z, s.z);
            s.w = fmaf(a[r], wbv[r].w, s.w);
        }
        const float av[4] = {fabsf(s.x), fabsf(s.y), fabsf(s.z), fabsf(s.w)};
#pragma unroll
        for (int j = 0; j < 4; ++j) {
            if (av[j] >= T) {
                unsigned k = (__float_as_uint(av[j]) - bitsT) >> 13;
                if (k > NBINS - 1u) k = NBINS - 1u;
                atomicAdd(&lcnt[k], 1u);
                atomicAdd(&lsum[k], (unsigned long long)(av[j] * fix));
            }
        }
    }
    __syncthreads();
    unsigned* __restrict__ gc = gcnt + (size_t)mat * NBINS;
    unsigned long long* __restrict__ gs = gsum + (size_t)mat * NBINS;
    for (int b = tid; b < NBINS; b += 256) {
        unsigned c = lcnt[b];
        if (c) {
            atomicAdd(&gc[b], c);
            atomicAdd(&gs[b], lsum[b]);
        }
    }
}

// ---------------------------------------------------------------------------
// Pass 3: one block, 1024 threads; suffix-scan histogram (integer, exact),
// top-64 cutoff, flag. Fully deterministic.
// ---------------------------------------------------------------------------
__global__ __launch_bounds__(1024) void k_select(
    unsigned* __restrict__ hdr, const unsigned* __restrict__ bmax,
    const unsigned* __restrict__ gcnt, const unsigned long long* __restrict__ gsum,
    const int* __restrict__ tsp) {
    __shared__ unsigned sc[NBINS];
    __shared__ unsigned long long ss[NBINS];
    __shared__ float res[2];
    __shared__ float Ms[2];
    __shared__ float redm[4];
    __shared__ int sB;
    const int b = threadIdx.x;

    for (int mat = 0; mat < 2; ++mat) {
        float M = block_max256(bmax, mat, b, redm);
        if (b == 0) Ms[mat] = M;
        __syncthreads();
    }

    for (int mat = 0; mat < 2; ++mat) {
        if (b == 0) sB = -1;
        const unsigned c0 = gcnt[(size_t)mat * NBINS + b];
        const unsigned long long s0 = gsum[(size_t)mat * NBINS + b];
        __syncthreads();           // previous iteration's readers done
        sc[b] = c0;
        ss[b] = s0;
        __syncthreads();
        // Hillis-Steele suffix scan (integer adds: exact, order-independent)
        for (int step = 1; step < NBINS; step <<= 1) {
            unsigned c2 = 0u; unsigned long long s2 = 0ull;
            if (b + step < NBINS) { c2 = sc[b + step]; s2 = ss[b + step]; }
            __syncthreads();
            sc[b] += c2;
            ss[b] += s2;
            __syncthreads();
        }
        if (sc[b] >= K_TOP && (b == NBINS - 1 || sc[b + 1] < K_TOP)) sB = b;
        __syncthreads();
        if (b == 0) {
            const double inv = (double)Ms[mat] * FIX_INV;  // decode units -> value
            float total;
            if (sB < 0) {
                total = (float)((double)ss[0] * inv);
            } else {
                const int B = sB;
                const unsigned cAbove = (B + 1 < NBINS) ? sc[B + 1] : 0u;
                const unsigned long long sAbove = (B + 1 < NBINS) ? ss[B + 1] : 0ull;
                const unsigned cb = sc[B] - cAbove;
                const unsigned long long sb = ss[B] - sAbove;
                const unsigned need = K_TOP - cAbove;
                total = (float)((double)sAbove * inv)
                      + (float)((double)sb * inv) * ((float)need / (float)cb);
            }
            res[mat] = total;
        }
        __syncthreads();
    }
    if (b == 0) {
        const int tr = (*tsp) % SUM_TIMESTEPS;
        const float scale = fmodf(ALPHA * (float)tr / (float)SUM_TIMESTEPS + BETA, ALPHA);
        const float temp_ratio = res[0] / (res[1] * scale);  // AVG_RATIO = 1.0
        hdr[4] = (temp_ratio > 1.0f) ? 1u : 0u;              // 1 -> matrix1
    }
}

// ---------------------------------------------------------------------------
// Kernel T (copy-shaped, ZERO barriers / ZERO LDS / NO k-loop):
// one wave = one (row-pair x 256-float i-slice) tile. Per lane: 2 h loads +
// 8 wb loads issued at once (no deps), 16 dot4s, 96-shuffle butterfly,
// lane0 writes a 64 B partial. 65536 independent waves (16384 blocks,
// 64 queued/CU) keep loads in flight continuously -> streams h like a copy.
// part[wg][16], wg = mp*16 + w: values [row&1][r] of t-partial for rows
// {2mp, 2mp+1} over i in [w*256, w*256+256).
// ---------------------------------------------------------------------------
__global__ __launch_bounds__(256) void k_t(
    const float* __restrict__ h,
    const float* __restrict__ wb1, const float* __restrict__ wb2,
    const unsigned* __restrict__ hdr,
    float* __restrict__ part) {
    const int tid = threadIdx.x;
    const int lane = tid & 63;
    const float* __restrict__ wb = hdr[4] ? wb1 : wb2;
    const int wg = blockIdx.x * 4 + (tid >> 6);   // [0, 65536)
    const int mp = wg >> 4;                        // row pair index
    const int w  = wg & 15;                        // i-slice index
    const size_t m = (size_t)mp * 2;
    const int i0 = w * 256 + lane * 4;

    // all 10 loads issue back-to-back (no dependencies)
    const f32x4 h0 = *(const f32x4*)(h + m * D + i0);
    const f32x4 h1 = *(const f32x4*)(h + (m + 1) * D + i0);
    f32x4 wbv[RANK];
#pragma unroll
    for (int r = 0; r < RANK; ++r)
        wbv[r] = *(const f32x4*)(wb + r * D + i0);

    float acc[16];
#pragma unroll
    for (int r = 0; r < RANK; ++r) {
        acc[r]     = dot4v(h0, wbv[r]);
        acc[8 + r] = dot4v(h1, wbv[r]);
    }
    // xor-butterfly: every lane ends with the slice-sum of all 16 values
#pragma unroll
    for (int off = 32; off; off >>= 1)
#pragma unroll
        for (int j = 0; j < 16; ++j)
            acc[j] += __shfl_xor(acc[j], off, 64);

    if (lane == 0) {
        float* __restrict__ dst = part + (size_t)wg * 16;
        const f32x4 v0 = {acc[0], acc[1], acc[2], acc[3]};
        const f32x4 v1 = {acc[4], acc[5], acc[6], acc[7]};
        const f32x4 v2 = {acc[8], acc[9], acc[10], acc[11]};
        const f32x4 v3 = {acc[12], acc[13], acc[14], acc[15]};
        *(f32x4*)(dst)      = v0;
        *(f32x4*)(dst + 4)  = v1;
        *(f32x4*)(dst + 8)  = v2;
        *(f32x4*)(dst + 12) = v3;
    }
}

// ---------------------------------------------------------------------------
// Kernel O (pure WRITE stream): out[m][o] = sum_r t[m][r] * wa[o][r].
// Preamble reduces the 16 i-slice partials per (row,r) in fixed order
// (deterministic), then streams 128 KB/block of nontemporal stores.
// ---------------------------------------------------------------------------
__global__ __launch_bounds__(256) void k_o(
    const float* __restrict__ part,
    const float* __restrict__ wa1, const float* __restrict__ wa2,
    const unsigned* __restrict__ hdr,
    float* __restrict__ out) {
    const int tid = threadIdx.x;
    const int wave = tid >> 6, lane = tid & 63;
    const float* __restrict__ wa = hdr[4] ? wa1 : wa2;
    const int cslice = blockIdx.x & 3;               // which 1024-col slice
    const size_t m0 = (size_t)(blockIdx.x >> 2) * 32;
    const int o0 = cslice * 1024 + wave * 256 + lane * 4;

    __shared__ float ts[32][8];  // reduced t for the block's 32 rows
    {
        const int row = tid >> 3, r = tid & 7;       // 256 threads = 32x8
        const size_t mp = (m0 >> 1) + (row >> 1);
        const int half = (row & 1) * 8;
        const float* __restrict__ p = part + (mp * 16) * 16 + half + r;
        float s = 0.f;
#pragma unroll
        for (int w = 0; w < 16; ++w) s += p[w * 16];  // fixed order: deterministic
        ts[row][r] = s;
    }

    f32x4 A[8];  // wa for this lane's 4 cols: A[2j]=col(o0+j) r0..3, A[2j+1]=r4..7
#pragma unroll
    for (int j = 0; j < 8; ++j)
        A[j] = *(const f32x4*)(wa + (size_t)o0 * RANK + j * 4);
    __syncthreads();

#pragma unroll 4
    for (int row = 0; row < 32; ++row) {
        const f32x4 t03 = *(const f32x4*)&ts[row][0];
        const f32x4 t47 = *(const f32x4*)&ts[row][4];
        f32x4 ov;
        ov.x = dot4v(A[0], t03) + dot4v(A[1], t47);
        ov.y = dot4v(A[2], t03) + dot4v(A[3], t47);
        ov.z = dot4v(A[4], t03) + dot4v(A[5], t47);
        ov.w = dot4v(A[6], t03) + dot4v(A[7], t47);
        __builtin_nontemporal_store(ov, (f32x4*)(out + (m0 + row) * D + o0));
    }
}

extern "C" void kernel_launch(void* const* d_in, const int* in_sizes, int n_in,
                              void* d_out, int out_size, void* d_ws, size_t ws_size,
                              hipStream_t stream) {
    const float* h   = (const float*)d_in[0];
    const float* wa1 = (const float*)d_in[1];
    const float* wb1 = (const float*)d_in[2];
    const float* wa2 = (const float*)d_in[3];
    const float* wb2 = (const float*)d_in[4];
    const int*   ts  = (const int*)d_in[5];
    float* out = (float*)d_out;

    const int rows = in_sizes[0] / D;  // 8192

    unsigned* hdr  = (unsigned*)d_ws;
    unsigned* gcnt = (unsigned*)((char*)d_ws + WS_GCNT_OFF);
    unsigned long long* gsum = (unsigned long long*)((char*)d_ws + WS_GSUM_OFF);
    unsigned* bmax = (unsigned*)((char*)d_ws + WS_BMAX_OFF);
    float*    part = (float*)((char*)d_ws + WS_PART_OFF);

    hipLaunchKernelGGL(k_pass_max, dim3(256, 2), dim3(256), 0, stream,
                       wa1, wb1, wa2, wb2, gcnt, bmax);
    hipLaunchKernelGGL(k_pass_hist, dim3(256, 2), dim3(256), 0, stream,
                       wa1, wb1, wa2, wb2, bmax, gcnt, gsum);
    hipLaunchKernelGGL(k_select, dim3(1), dim3(1024), 0, stream,
                       hdr, bmax, gcnt, gsum, ts);
    // waves = rows/2 * 16 slices; 4 waves per 256-thr block
    hipLaunchKernelGGL(k_t, dim3((rows / 2) * 16 / 4), dim3(256), 0, stream,
                       h, wb1, wb2, hdr, part);
    hipLaunchKernelGGL(k_o, dim3(4 * (rows / 32)), dim3(256), 0, stream,
                       part, wa1, wa2, hdr, out);
}

// Round 13
// 107.691 us; speedup vs baseline: 1.2564x; 1.2564x over previous
//
#include <hip/hip_runtime.h>
#include <stdint.h>

#define D 4096
#define RANK 8
#define ALPHA 1.5f
#define BETA 0.5f
#define SUM_TIMESTEPS 28000
#define K_TOP 64
#define NBINS 1024

typedef float f32x4 __attribute__((ext_vector_type(4)));

// ws layout (bytes):
//   [0, 256)            : u32 hdr[]: [4]=flag (written unconditionally each call)
//   [256, 256+8K)       : u32 gcnt[2][NBINS]   (zeroed by k_pass_max each call)
//   [8448, 8448+16K)    : u64 gsum[2][NBINS]   (zeroed by k_pass_max each call)
//   [24832, 24832+2K)   : u32 bmax[2][256]     (written unconditionally each call)
//   [26880, +256K)      : f32 t[8192][8]       (written unconditionally each call)
#define WS_GCNT_OFF 256
#define WS_GSUM_OFF (256 + 2 * NBINS * 4)
#define WS_BMAX_OFF (WS_GSUM_OFF + 2 * NBINS * 8)
#define WS_T_OFF    (WS_BMAX_OFF + 2048)

// fixed-point scale: 2^38 / max  (sum of 16.7M maximal values still < 2^62)
#define FIX_NUM 2.74877906944e11f
#define FIX_INV 3.637978807091713e-12   // 2^-38

__device__ __forceinline__ float dot4v(f32x4 a, f32x4 b) {
    return fmaf(a.x, b.x, fmaf(a.y, b.y, fmaf(a.z, b.z, a.w * b.w)));
}

// ---------------------------------------------------------------------------
// Pass 1: per-block max of |wa@wb| -> bmax[mat][bid]. wa slice staged in LDS.
// Zeroes gcnt/gsum for the NEXT kernel. grid (256, 2), block 256.
// ---------------------------------------------------------------------------
__global__ __launch_bounds__(256) void k_pass_max(
    const float* __restrict__ wa1, const float* __restrict__ wb1,
    const float* __restrict__ wa2, const float* __restrict__ wb2,
    unsigned* __restrict__ gz, unsigned* __restrict__ bmax) {
    const int tid = threadIdx.x;
    const int mat = blockIdx.y;
    const int bid = blockIdx.x;
    // zero gcnt/gsum stripes (consumed by the NEXT kernel, so no race)
    if (mat == 0 && tid < 24) gz[bid * 24 + tid] = 0u;

    const float* __restrict__ wa = mat ? wa2 : wa1;
    const float* __restrict__ wb = mat ? wb2 : wb1;
    const int i0 = (bid & 3) * 1024 + tid * 4;
    const int obase = (bid >> 2) * 64;

    __shared__ float was[64][8];  // 2 KB wa slice
    if (tid < 128)
        ((f32x4*)was)[tid] = ((const f32x4*)(wa + (size_t)obase * RANK))[tid];

    f32x4 wbv[RANK];
#pragma unroll
    for (int r = 0; r < RANK; ++r)
        wbv[r] = *(const f32x4*)(wb + r * D + i0);
    __syncthreads();

    float vmax = 0.f;
#pragma unroll 4
    for (int oo = 0; oo < 64; ++oo) {
        const f32x4 w03 = *(const f32x4*)&was[oo][0];  // LDS broadcast
        const f32x4 w47 = *(const f32x4*)&was[oo][4];
        f32x4 s = {0.f, 0.f, 0.f, 0.f};
        const float a[8] = {w03.x, w03.y, w03.z, w03.w, w47.x, w47.y, w47.z, w47.w};
#pragma unroll
        for (int r = 0; r < RANK; ++r) {
            s.x = fmaf(a[r], wbv[r].x, s.x);
            s.y = fmaf(a[r], wbv[r].y, s.y);
            s.z = fmaf(a[r], wbv[r].z, s.z);
            s.w = fmaf(a[r], wbv[r].w, s.w);
        }
        vmax = fmaxf(vmax, fmaxf(fmaxf(fabsf(s.x), fabsf(s.y)),
                                 fmaxf(fabsf(s.z), fabsf(s.w))));
    }
    for (int off = 32; off; off >>= 1)
        vmax = fmaxf(vmax, __shfl_xor(vmax, off, 64));
    __shared__ float smax[4];
    const int wave = tid >> 6, lane = tid & 63;
    if (lane == 0) smax[wave] = vmax;
    __syncthreads();
    if (tid == 0) {
        float m = fmaxf(fmaxf(smax[0], smax[1]), fmaxf(smax[2], smax[3]));
        bmax[mat * 256 + bid] = __float_as_uint(m);  // unconditional write
    }
}

// ---------------------------------------------------------------------------
// helper: block-level max over 256 bmax entries (block must be >=256 thr)
// ---------------------------------------------------------------------------
__device__ __forceinline__ float block_max256(const unsigned* __restrict__ bmax,
                                              int mat, int tid, float* redm) {
    const int wave = tid >> 6, lane = tid & 63;
    float m = 0.f;
    if (tid < 256) m = __uint_as_float(bmax[mat * 256 + tid]);
    for (int off = 32; off; off >>= 1)
        m = fmaxf(m, __shfl_xor(m, off, 64));
    if (tid < 256 && lane == 0) redm[wave] = m;
    __syncthreads();
    return fmaxf(fmaxf(redm[0], redm[1]), fmaxf(redm[2], redm[3]));
}

// ---------------------------------------------------------------------------
// Pass 2: histogram all |elem| >= 0.5*max. Counts u32, sums u64 fixed-point
// (order-independent integer atomics -> bit-deterministic across replays).
// wa slice staged in LDS. grid (256, 2), block 256.
// ---------------------------------------------------------------------------
__global__ __launch_bounds__(256) void k_pass_hist(
    const float* __restrict__ wa1, const float* __restrict__ wb1,
    const float* __restrict__ wa2, const float* __restrict__ wb2,
    const unsigned* __restrict__ bmax,
    unsigned* __restrict__ gcnt, unsigned long long* __restrict__ gsum) {
    __shared__ unsigned lcnt[NBINS];
    __shared__ unsigned long long lsum[NBINS];
    __shared__ float was[64][8];
    __shared__ float redm[4];
    const int tid = threadIdx.x;
    const int mat = blockIdx.y;
    for (int b = tid; b < NBINS; b += 256) { lcnt[b] = 0u; lsum[b] = 0ull; }

    const float* __restrict__ wa = mat ? wa2 : wa1;
    const float* __restrict__ wb = mat ? wb2 : wb1;
    const int i0 = (blockIdx.x & 3) * 1024 + tid * 4;
    const int obase = (blockIdx.x >> 2) * 64;
    if (tid < 128)
        ((f32x4*)was)[tid] = ((const f32x4*)(wa + (size_t)obase * RANK))[tid];

    // (block_max256 contains the needed barrier)
    const float M = block_max256(bmax, mat, tid, redm);
    const float T = 0.5f * M;
    const float fix = FIX_NUM / M;
    const unsigned bitsT = __float_as_uint(T);

    f32x4 wbv[RANK];
#pragma unroll
    for (int r = 0; r < RANK; ++r)
        wbv[r] = *(const f32x4*)(wb + r * D + i0);

#pragma unroll 2
    for (int oo = 0; oo < 64; ++oo) {
        const f32x4 w03 = *(const f32x4*)&was[oo][0];
        const f32x4 w47 = *(const f32x4*)&was[oo][4];
        f32x4 s = {0.f, 0.f, 0.f, 0.f};
        const float a[8] = {w03.x, w03.y, w03.z, w03.w, w47.x, w47.y, w47.z, w47.w};
#pragma unroll
        for (int r = 0; r < RANK; ++r) {
            s.x = fmaf(a[r], wbv[r].x, s.x);
            s.y = fmaf(a[r], wbv[r].y, s.y);
            s.z = fmaf(a[r], wbv[r].z, s.z);
            s.w = fmaf(a[r], wbv[r].w, s.w);
        }
        const float av[4] = {fabsf(s.x), fabsf(s.y), fabsf(s.z), fabsf(s.w)};
#pragma unroll
        for (int j = 0; j < 4; ++j) {
            if (av[j] >= T) {
                unsigned k = (__float_as_uint(av[j]) - bitsT) >> 13;
                if (k > NBINS - 1u) k = NBINS - 1u;
                atomicAdd(&lcnt[k], 1u);
                atomicAdd(&lsum[k], (unsigned long long)(av[j] * fix));
            }
        }
    }
    __syncthreads();
    unsigned* __restrict__ gc = gcnt + (size_t)mat * NBINS;
    unsigned long long* __restrict__ gs = gsum + (size_t)mat * NBINS;
    for (int b = tid; b < NBINS; b += 256) {
        unsigned c = lcnt[b];
        if (c) {
            atomicAdd(&gc[b], c);
            atomicAdd(&gs[b], lsum[b]);
        }
    }
}

// ---------------------------------------------------------------------------
// Pass 3: one block, 1024 threads; suffix-scan histogram (integer, exact),
// top-64 cutoff, flag. Fully deterministic.
// ---------------------------------------------------------------------------
__global__ __launch_bounds__(1024) void k_select(
    unsigned* __restrict__ hdr, const unsigned* __restrict__ bmax,
    const unsigned* __restrict__ gcnt, const unsigned long long* __restrict__ gsum,
    const int* __restrict__ tsp) {
    __shared__ unsigned sc[NBINS];
    __shared__ unsigned long long ss[NBINS];
    __shared__ float res[2];
    __shared__ float Ms[2];
    __shared__ float redm[4];
    __shared__ int sB;
    const int b = threadIdx.x;

    for (int mat = 0; mat < 2; ++mat) {
        float M = block_max256(bmax, mat, b, redm);
        if (b == 0) Ms[mat] = M;
        __syncthreads();
    }

    for (int mat = 0; mat < 2; ++mat) {
        if (b == 0) sB = -1;
        const unsigned c0 = gcnt[(size_t)mat * NBINS + b];
        const unsigned long long s0 = gsum[(size_t)mat * NBINS + b];
        __syncthreads();           // previous iteration's readers done
        sc[b] = c0;
        ss[b] = s0;
        __syncthreads();
        // Hillis-Steele suffix scan (integer adds: exact, order-independent)
        for (int step = 1; step < NBINS; step <<= 1) {
            unsigned c2 = 0u; unsigned long long s2 = 0ull;
            if (b + step < NBINS) { c2 = sc[b + step]; s2 = ss[b + step]; }
            __syncthreads();
            sc[b] += c2;
            ss[b] += s2;
            __syncthreads();
        }
        if (sc[b] >= K_TOP && (b == NBINS - 1 || sc[b + 1] < K_TOP)) sB = b;
        __syncthreads();
        if (b == 0) {
            const double inv = (double)Ms[mat] * FIX_INV;  // decode units -> value
            float total;
            if (sB < 0) {
                total = (float)((double)ss[0] * inv);
            } else {
                const int B = sB;
                const unsigned cAbove = (B + 1 < NBINS) ? sc[B + 1] : 0u;
                const unsigned long long sAbove = (B + 1 < NBINS) ? ss[B + 1] : 0ull;
                const unsigned cb = sc[B] - cAbove;
                const unsigned long long sb = ss[B] - sAbove;
                const unsigned need = K_TOP - cAbove;
                total = (float)((double)sAbove * inv)
                      + (float)((double)sb * inv) * ((float)need / (float)cb);
            }
            res[mat] = total;
        }
        __syncthreads();
    }
    if (b == 0) {
        const int tr = (*tsp) % SUM_TIMESTEPS;
        const float scale = fmodf(ALPHA * (float)tr / (float)SUM_TIMESTEPS + BETA, ALPHA);
        const float temp_ratio = res[0] / (res[1] * scale);  // AVG_RATIO = 1.0
        hdr[4] = (temp_ratio > 1.0f) ? 1u : 0u;              // 1 -> matrix1
    }
}

// ---------------------------------------------------------------------------
// Kernel T: whole wb (128 KiB) in DYNAMIC LDS, staged ONCE per block; then a
// BARRIER-FREE steady state. Block = 1024 thr (16 waves), 1 block/CU,
// grid 256. Wave owns 2 rows end-to-end: per k-step 2 coalesced h loads +
// 8 LDS broadcast b128 + 64 FMA, no syncs -> loads pipeline across k-steps
// and waves never stop issuing reads. Butterfly amortized over 32 KB of h.
// ---------------------------------------------------------------------------
__global__ __launch_bounds__(1024) void k_t(
    const float* __restrict__ h,
    const float* __restrict__ wb1, const float* __restrict__ wb2,
    const unsigned* __restrict__ hdr,
    float* __restrict__ t) {
    extern __shared__ float wbs[];  // [8][4096] = 128 KiB
    const int tid = threadIdx.x;
    const int wave = tid >> 6, lane = tid & 63;
    const float* __restrict__ wb = hdr[4] ? wb1 : wb2;

    // stage all of wb: 8192 f32x4 / 1024 thr = 8 each, coalesced
    {
        const f32x4* __restrict__ src = (const f32x4*)wb;
        f32x4* __restrict__ dst = (f32x4*)wbs;
#pragma unroll
        for (int s = 0; s < 8; ++s)
            dst[s * 1024 + tid] = src[s * 1024 + tid];
    }
    __syncthreads();  // the ONLY barrier

    const size_t m0 = (size_t)blockIdx.x * 32 + wave * 2;

    float acc[2][RANK];
#pragma unroll
    for (int row = 0; row < 2; ++row)
#pragma unroll
        for (int r = 0; r < RANK; ++r) acc[row][r] = 0.f;

#pragma unroll 2
    for (int k = 0; k < 16; ++k) {
        const int i = k * 256 + lane * 4;
        const f32x4 h0 = *(const f32x4*)(h + m0 * D + i);
        const f32x4 h1 = *(const f32x4*)(h + (m0 + 1) * D + i);
        f32x4 wbv[RANK];
#pragma unroll
        for (int r = 0; r < RANK; ++r)
            wbv[r] = *(const f32x4*)&wbs[r * D + i];
#pragma unroll
        for (int r = 0; r < RANK; ++r) {
            acc[0][r] = fmaf(h0.x, wbv[r].x, fmaf(h0.y, wbv[r].y,
                        fmaf(h0.z, wbv[r].z, fmaf(h0.w, wbv[r].w, acc[0][r]))));
            acc[1][r] = fmaf(h1.x, wbv[r].x, fmaf(h1.y, wbv[r].y,
                        fmaf(h1.z, wbv[r].z, fmaf(h1.w, wbv[r].w, acc[1][r]))));
        }
    }

    // butterfly reduce (amortized over 32 KB of h per wave); lane0 writes t
#pragma unroll
    for (int row = 0; row < 2; ++row)
#pragma unroll
        for (int r = 0; r < RANK; ++r)
#pragma unroll
            for (int off = 32; off; off >>= 1)
                acc[row][r] += __shfl_xor(acc[row][r], off, 64);
    if (lane == 0) {
        const f32x4 v0 = {acc[0][0], acc[0][1], acc[0][2], acc[0][3]};
        const f32x4 v1 = {acc[0][4], acc[0][5], acc[0][6], acc[0][7]};
        const f32x4 v2 = {acc[1][0], acc[1][1], acc[1][2], acc[1][3]};
        const f32x4 v3 = {acc[1][4], acc[1][5], acc[1][6], acc[1][7]};
        f32x4* __restrict__ dst = (f32x4*)(t + m0 * RANK);
        dst[0] = v0; dst[1] = v1; dst[2] = v2; dst[3] = v3;
    }
}

// ---------------------------------------------------------------------------
// Kernel O (pure WRITE stream): out[m][o] = sum_r t[m][r] * wa[o][r].
// R10 shape but PLAIN stores (fillBuffer hits 7 TB/s with plain stores;
// the nt path measured ~4.8).
// ---------------------------------------------------------------------------
__global__ __launch_bounds__(256) void k_o(
    const float* __restrict__ t,
    const float* __restrict__ wa1, const float* __restrict__ wa2,
    const unsigned* __restrict__ hdr,
    float* __restrict__ out) {
    const int tid = threadIdx.x;
    const int wave = tid >> 6, lane = tid & 63;
    const float* __restrict__ wa = hdr[4] ? wa1 : wa2;
    const int cslice = blockIdx.x & 3;               // which 1024-col slice
    const size_t m0 = (size_t)(blockIdx.x >> 2) * 32;
    const int o0 = cslice * 1024 + wave * 256 + lane * 4;

    __shared__ float ts[32][8];  // 1 KB t tile
    if (tid < 64)
        ((f32x4*)ts)[tid] = *(const f32x4*)(t + m0 * RANK + tid * 4);

    f32x4 A[8];  // wa for this lane's 4 cols: A[2j]=col(o0+j) r0..3, A[2j+1]=r4..7
#pragma unroll
    for (int j = 0; j < 8; ++j)
        A[j] = *(const f32x4*)(wa + (size_t)o0 * RANK + j * 4);
    __syncthreads();

#pragma unroll 4
    for (int row = 0; row < 32; ++row) {
        const f32x4 t03 = *(const f32x4*)&ts[row][0];
        const f32x4 t47 = *(const f32x4*)&ts[row][4];
        f32x4 ov;
        ov.x = dot4v(A[0], t03) + dot4v(A[1], t47);
        ov.y = dot4v(A[2], t03) + dot4v(A[3], t47);
        ov.z = dot4v(A[4], t03) + dot4v(A[5], t47);
        ov.w = dot4v(A[6], t03) + dot4v(A[7], t47);
        *(f32x4*)(out + (m0 + row) * D + o0) = ov;  // plain store
    }
}

extern "C" void kernel_launch(void* const* d_in, const int* in_sizes, int n_in,
                              void* d_out, int out_size, void* d_ws, size_t ws_size,
                              hipStream_t stream) {
    const float* h   = (const float*)d_in[0];
    const float* wa1 = (const float*)d_in[1];
    const float* wb1 = (const float*)d_in[2];
    const float* wa2 = (const float*)d_in[3];
    const float* wb2 = (const float*)d_in[4];
    const int*   ts  = (const int*)d_in[5];
    float* out = (float*)d_out;

    const int rows = in_sizes[0] / D;  // 8192

    unsigned* hdr  = (unsigned*)d_ws;
    unsigned* gcnt = (unsigned*)((char*)d_ws + WS_GCNT_OFF);
    unsigned long long* gsum = (unsigned long long*)((char*)d_ws + WS_GSUM_OFF);
    unsigned* bmax = (unsigned*)((char*)d_ws + WS_BMAX_OFF);
    float*    tbuf = (float*)((char*)d_ws + WS_T_OFF);

    // opt in to >64 KiB dynamic LDS for k_t (idempotent; host-side, capture-safe)
    (void)hipFuncSetAttribute((const void*)k_t,
                              hipFuncAttributeMaxDynamicSharedMemorySize,
                              RANK * D * (int)sizeof(float));

    hipLaunchKernelGGL(k_pass_max, dim3(256, 2), dim3(256), 0, stream,
                       wa1, wb1, wa2, wb2, gcnt, bmax);
    hipLaunchKernelGGL(k_pass_hist, dim3(256, 2), dim3(256), 0, stream,
                       wa1, wb1, wa2, wb2, bmax, gcnt, gsum);
    hipLaunchKernelGGL(k_select, dim3(1), dim3(1024), 0, stream,
                       hdr, bmax, gcnt, gsum, ts);
    hipLaunchKernelGGL(k_t, dim3(rows / 32), dim3(1024),
                       RANK * D * sizeof(float), stream,
                       h, wb1, wb2, hdr, tbuf);
    hipLaunchKernelGGL(k_o, dim3(4 * (rows / 32)), dim3(256), 0, stream,
                       tbuf, wa1, wa2, hdr, out);
}

// Round 14
// 97.878 us; speedup vs baseline: 1.3824x; 1.1002x over previous
//
#include <hip/hip_runtime.h>
#include <stdint.h>

#define D 4096
#define RANK 8
#define ALPHA 1.5f
#define BETA 0.5f
#define SUM_TIMESTEPS 28000
#define K_TOP 64
#define NBINS 1024

typedef float f32x4 __attribute__((ext_vector_type(4)));

// ws layout (bytes):
//   [0, 256)            : u32 hdr[]: [4]=flag (written unconditionally each call)
//   [256, 256+8K)       : u32 gcnt[2][NBINS]   (zeroed by k_pass_max each call)
//   [8448, 8448+16K)    : u64 gsum[2][NBINS]   (zeroed by k_pass_max each call)
//   [24832, 24832+2K)   : u32 bmax[2][256]     (written unconditionally each call)
//   [26880, +256K)      : f32 t[8192][8]       (written unconditionally each call)
#define WS_GCNT_OFF 256
#define WS_GSUM_OFF (256 + 2 * NBINS * 4)
#define WS_BMAX_OFF (WS_GSUM_OFF + 2 * NBINS * 8)
#define WS_T_OFF    (WS_BMAX_OFF + 2048)

// fixed-point scale: 2^38 / max  (sum of 16.7M maximal values still < 2^62)
#define FIX_NUM 2.74877906944e11f
#define FIX_INV 3.637978807091713e-12   // 2^-38

__device__ __forceinline__ float dot4v(f32x4 a, f32x4 b) {
    return fmaf(a.x, b.x, fmaf(a.y, b.y, fmaf(a.z, b.z, a.w * b.w)));
}

// ---------------------------------------------------------------------------
// Pass 1: per-block max of |wa@wb| -> bmax[mat][bid]. wa slice staged in LDS.
// Zeroes gcnt/gsum for the NEXT kernel. grid (256, 2), block 256.
// ---------------------------------------------------------------------------
__global__ __launch_bounds__(256) void k_pass_max(
    const float* __restrict__ wa1, const float* __restrict__ wb1,
    const float* __restrict__ wa2, const float* __restrict__ wb2,
    unsigned* __restrict__ gz, unsigned* __restrict__ bmax) {
    const int tid = threadIdx.x;
    const int mat = blockIdx.y;
    const int bid = blockIdx.x;
    // zero gcnt/gsum stripes (consumed by the NEXT kernel, so no race)
    if (mat == 0 && tid < 24) gz[bid * 24 + tid] = 0u;

    const float* __restrict__ wa = mat ? wa2 : wa1;
    const float* __restrict__ wb = mat ? wb2 : wb1;
    const int i0 = (bid & 3) * 1024 + tid * 4;
    const int obase = (bid >> 2) * 64;

    __shared__ float was[64][8];  // 2 KB wa slice
    if (tid < 128)
        ((f32x4*)was)[tid] = ((const f32x4*)(wa + (size_t)obase * RANK))[tid];

    f32x4 wbv[RANK];
#pragma unroll
    for (int r = 0; r < RANK; ++r)
        wbv[r] = *(const f32x4*)(wb + r * D + i0);
    __syncthreads();

    float vmax = 0.f;
#pragma unroll 4
    for (int oo = 0; oo < 64; ++oo) {
        const f32x4 w03 = *(const f32x4*)&was[oo][0];  // LDS broadcast
        const f32x4 w47 = *(const f32x4*)&was[oo][4];
        f32x4 s = {0.f, 0.f, 0.f, 0.f};
        const float a[8] = {w03.x, w03.y, w03.z, w03.w, w47.x, w47.y, w47.z, w47.w};
#pragma unroll
        for (int r = 0; r < RANK; ++r) {
            s.x = fmaf(a[r], wbv[r].x, s.x);
            s.y = fmaf(a[r], wbv[r].y, s.y);
            s.z = fmaf(a[r], wbv[r].z, s.z);
            s.w = fmaf(a[r], wbv[r].w, s.w);
        }
        vmax = fmaxf(vmax, fmaxf(fmaxf(fabsf(s.x), fabsf(s.y)),
                                 fmaxf(fabsf(s.z), fabsf(s.w))));
    }
    for (int off = 32; off; off >>= 1)
        vmax = fmaxf(vmax, __shfl_xor(vmax, off, 64));
    __shared__ float smax[4];
    const int wave = tid >> 6, lane = tid & 63;
    if (lane == 0) smax[wave] = vmax;
    __syncthreads();
    if (tid == 0) {
        float m = fmaxf(fmaxf(smax[0], smax[1]), fmaxf(smax[2], smax[3]));
        bmax[mat * 256 + bid] = __float_as_uint(m);  // unconditional write
    }
}

// ---------------------------------------------------------------------------
// helper: block-level max over 256 bmax entries (block must be >=256 thr)
// ---------------------------------------------------------------------------
__device__ __forceinline__ float block_max256(const unsigned* __restrict__ bmax,
                                              int mat, int tid, float* redm) {
    const int wave = tid >> 6, lane = tid & 63;
    float m = 0.f;
    if (tid < 256) m = __uint_as_float(bmax[mat * 256 + tid]);
    for (int off = 32; off; off >>= 1)
        m = fmaxf(m, __shfl_xor(m, off, 64));
    if (tid < 256 && lane == 0) redm[wave] = m;
    __syncthreads();
    return fmaxf(fmaxf(redm[0], redm[1]), fmaxf(redm[2], redm[3]));
}

// ---------------------------------------------------------------------------
// Pass 2: histogram all |elem| >= 0.5*max. Counts u32, sums u64 fixed-point
// (order-independent integer atomics -> bit-deterministic across replays).
// wa slice staged in LDS. grid (256, 2), block 256.
// ---------------------------------------------------------------------------
__global__ __launch_bounds__(256) void k_pass_hist(
    const float* __restrict__ wa1, const float* __restrict__ wb1,
    const float* __restrict__ wa2, const float* __restrict__ wb2,
    const unsigned* __restrict__ bmax,
    unsigned* __restrict__ gcnt, unsigned long long* __restrict__ gsum) {
    __shared__ unsigned lcnt[NBINS];
    __shared__ unsigned long long lsum[NBINS];
    __shared__ float was[64][8];
    __shared__ float redm[4];
    const int tid = threadIdx.x;
    const int mat = blockIdx.y;
    for (int b = tid; b < NBINS; b += 256) { lcnt[b] = 0u; lsum[b] = 0ull; }

    const float* __restrict__ wa = mat ? wa2 : wa1;
    const float* __restrict__ wb = mat ? wb2 : wb1;
    const int i0 = (blockIdx.x & 3) * 1024 + tid * 4;
    const int obase = (blockIdx.x >> 2) * 64;
    if (tid < 128)
        ((f32x4*)was)[tid] = ((const f32x4*)(wa + (size_t)obase * RANK))[tid];

    // (block_max256 contains the needed barrier)
    const float M = block_max256(bmax, mat, tid, redm);
    const float T = 0.5f * M;
    const float fix = FIX_NUM / M;
    const unsigned bitsT = __float_as_uint(T);

    f32x4 wbv[RANK];
#pragma unroll
    for (int r = 0; r < RANK; ++r)
        wbv[r] = *(const f32x4*)(wb + r * D + i0);

#pragma unroll 2
    for (int oo = 0; oo < 64; ++oo) {
        const f32x4 w03 = *(const f32x4*)&was[oo][0];
        const f32x4 w47 = *(const f32x4*)&was[oo][4];
        f32x4 s = {0.f, 0.f, 0.f, 0.f};
        const float a[8] = {w03.x, w03.y, w03.z, w03.w, w47.x, w47.y, w47.z, w47.w};
#pragma unroll
        for (int r = 0; r < RANK; ++r) {
            s.x = fmaf(a[r], wbv[r].x, s.x);
            s.y = fmaf(a[r], wbv[r].y, s.y);
            s.z = fmaf(a[r], wbv[r].z, s.z);
            s.w = fmaf(a[r], wbv[r].w, s.w);
        }
        const float av[4] = {fabsf(s.x), fabsf(s.y), fabsf(s.z), fabsf(s.w)};
#pragma unroll
        for (int j = 0; j < 4; ++j) {
            if (av[j] >= T) {
                unsigned k = (__float_as_uint(av[j]) - bitsT) >> 13;
                if (k > NBINS - 1u) k = NBINS - 1u;
                atomicAdd(&lcnt[k], 1u);
                atomicAdd(&lsum[k], (unsigned long long)(av[j] * fix));
            }
        }
    }
    __syncthreads();
    unsigned* __restrict__ gc = gcnt + (size_t)mat * NBINS;
    unsigned long long* __restrict__ gs = gsum + (size_t)mat * NBINS;
    for (int b = tid; b < NBINS; b += 256) {
        unsigned c = lcnt[b];
        if (c) {
            atomicAdd(&gc[b], c);
            atomicAdd(&gs[b], lsum[b]);
        }
    }
}

// ---------------------------------------------------------------------------
// Pass 3: one block, 1024 threads; suffix-scan histogram (integer, exact),
// top-64 cutoff, flag. Fully deterministic.
// ---------------------------------------------------------------------------
__global__ __launch_bounds__(1024) void k_select(
    unsigned* __restrict__ hdr, const unsigned* __restrict__ bmax,
    const unsigned* __restrict__ gcnt, const unsigned long long* __restrict__ gsum,
    const int* __restrict__ tsp) {
    __shared__ unsigned sc[NBINS];
    __shared__ unsigned long long ss[NBINS];
    __shared__ float res[2];
    __shared__ float Ms[2];
    __shared__ float redm[4];
    __shared__ int sB;
    const int b = threadIdx.x;

    for (int mat = 0; mat < 2; ++mat) {
        float M = block_max256(bmax, mat, b, redm);
        if (b == 0) Ms[mat] = M;
        __syncthreads();
    }

    for (int mat = 0; mat < 2; ++mat) {
        if (b == 0) sB = -1;
        const unsigned c0 = gcnt[(size_t)mat * NBINS + b];
        const unsigned long long s0 = gsum[(size_t)mat * NBINS + b];
        __syncthreads();           // previous iteration's readers done
        sc[b] = c0;
        ss[b] = s0;
        __syncthreads();
        // Hillis-Steele suffix scan (integer adds: exact, order-independent)
        for (int step = 1; step < NBINS; step <<= 1) {
            unsigned c2 = 0u; unsigned long long s2 = 0ull;
            if (b + step < NBINS) { c2 = sc[b + step]; s2 = ss[b + step]; }
            __syncthreads();
            sc[b] += c2;
            ss[b] += s2;
            __syncthreads();
        }
        if (sc[b] >= K_TOP && (b == NBINS - 1 || sc[b + 1] < K_TOP)) sB = b;
        __syncthreads();
        if (b == 0) {
            const double inv = (double)Ms[mat] * FIX_INV;  // decode units -> value
            float total;
            if (sB < 0) {
                total = (float)((double)ss[0] * inv);
            } else {
                const int B = sB;
                const unsigned cAbove = (B + 1 < NBINS) ? sc[B + 1] : 0u;
                const unsigned long long sAbove = (B + 1 < NBINS) ? ss[B + 1] : 0ull;
                const unsigned cb = sc[B] - cAbove;
                const unsigned long long sb = ss[B] - sAbove;
                const unsigned need = K_TOP - cAbove;
                total = (float)((double)sAbove * inv)
                      + (float)((double)sb * inv) * ((float)need / (float)cb);
            }
            res[mat] = total;
        }
        __syncthreads();
    }
    if (b == 0) {
        const int tr = (*tsp) % SUM_TIMESTEPS;
        const float scale = fmodf(ALPHA * (float)tr / (float)SUM_TIMESTEPS + BETA, ALPHA);
        const float temp_ratio = res[0] / (res[1] * scale);  // AVG_RATIO = 1.0
        hdr[4] = (temp_ratio > 1.0f) ? 1u : 0u;              // 1 -> matrix1
    }
}

// ---------------------------------------------------------------------------
// Kernel T: BARRIER-FREE, LDS-FREE, explicitly software-pipelined.
// Wave owns 4 rows end-to-end; two register sets (4 h + 8 wb loads) ping-pong:
// while FMA-ing set A, set B's 12 loads are in flight — and NO barrier ever
// drains them (the R7-R10 structures lost ~60% read duty to the compiler's
// mandatory vmcnt(0) before each s_barrier). wb comes straight from L2
// (256 MB aggregate ~ 7 us, hidden under the h stream). Butterfly once per
// wave per 64 KB of h (3 shuffles/KB).
// grid 512 x 256 thr (2048 waves x 4 rows = 8192 rows).
// ---------------------------------------------------------------------------
__device__ __forceinline__ void kt_load(const float* __restrict__ h,
                                        const float* __restrict__ wb,
                                        size_t m0, int i,
                                        f32x4 hv[4], f32x4 wv[RANK]) {
#pragma unroll
    for (int row = 0; row < 4; ++row)
        hv[row] = *(const f32x4*)(h + (m0 + row) * D + i);
#pragma unroll
    for (int r = 0; r < RANK; ++r)
        wv[r] = *(const f32x4*)(wb + r * D + i);
}

__device__ __forceinline__ void kt_fma(const f32x4 hv[4], const f32x4 wv[RANK],
                                       float acc[4][RANK]) {
#pragma unroll
    for (int row = 0; row < 4; ++row)
#pragma unroll
        for (int r = 0; r < RANK; ++r)
            acc[row][r] = fmaf(hv[row].x, wv[r].x,
                          fmaf(hv[row].y, wv[r].y,
                          fmaf(hv[row].z, wv[r].z,
                          fmaf(hv[row].w, wv[r].w, acc[row][r]))));
}

__global__ __launch_bounds__(256) void k_t(
    const float* __restrict__ h,
    const float* __restrict__ wb1, const float* __restrict__ wb2,
    const unsigned* __restrict__ hdr,
    float* __restrict__ t) {
    const int tid = threadIdx.x;
    const int wave = tid >> 6, lane = tid & 63;
    const float* __restrict__ wb = hdr[4] ? wb1 : wb2;
    const size_t m0 = ((size_t)blockIdx.x * 4 + wave) * 4;
    const int ib = lane * 4;

    float acc[4][RANK];
#pragma unroll
    for (int row = 0; row < 4; ++row)
#pragma unroll
        for (int r = 0; r < RANK; ++r) acc[row][r] = 0.f;

    f32x4 hA[4], wA[RANK], hB[4], wB[RANK];
    kt_load(h, wb, m0, ib, hA, wA);                       // prologue: step 0
#pragma unroll
    for (int k = 0; k < 16; k += 2) {
        kt_load(h, wb, m0, (k + 1) * 256 + ib, hB, wB);   // issue k+1
        kt_fma(hA, wA, acc);                              // compute k
        if (k < 14)
            kt_load(h, wb, m0, (k + 2) * 256 + ib, hA, wA);  // issue k+2
        kt_fma(hB, wB, acc);                              // compute k+1
    }

    // butterfly reduce over lanes (amortized: 192 shuffles per 64 KB of h)
#pragma unroll
    for (int row = 0; row < 4; ++row)
#pragma unroll
        for (int r = 0; r < RANK; ++r)
#pragma unroll
            for (int off = 32; off; off >>= 1)
                acc[row][r] += __shfl_xor(acc[row][r], off, 64);
    if (lane == 0) {
#pragma unroll
        for (int row = 0; row < 4; ++row) {
            const f32x4 v0 = {acc[row][0], acc[row][1], acc[row][2], acc[row][3]};
            const f32x4 v1 = {acc[row][4], acc[row][5], acc[row][6], acc[row][7]};
            f32x4* __restrict__ dst = (f32x4*)(t + (m0 + row) * RANK);
            dst[0] = v0; dst[1] = v1;
        }
    }
}

// ---------------------------------------------------------------------------
// Kernel O (pure WRITE stream): out[m][o] = sum_r t[m][r] * wa[o][r].
// Plain stores. Unchanged from R13.
// ---------------------------------------------------------------------------
__global__ __launch_bounds__(256) void k_o(
    const float* __restrict__ t,
    const float* __restrict__ wa1, const float* __restrict__ wa2,
    const unsigned* __restrict__ hdr,
    float* __restrict__ out) {
    const int tid = threadIdx.x;
    const int wave = tid >> 6, lane = tid & 63;
    const float* __restrict__ wa = hdr[4] ? wa1 : wa2;
    const int cslice = blockIdx.x & 3;               // which 1024-col slice
    const size_t m0 = (size_t)(blockIdx.x >> 2) * 32;
    const int o0 = cslice * 1024 + wave * 256 + lane * 4;

    __shared__ float ts[32][8];  // 1 KB t tile
    if (tid < 64)
        ((f32x4*)ts)[tid] = *(const f32x4*)(t + m0 * RANK + tid * 4);

    f32x4 A[8];  // wa for this lane's 4 cols: A[2j]=col(o0+j) r0..3, A[2j+1]=r4..7
#pragma unroll
    for (int j = 0; j < 8; ++j)
        A[j] = *(const f32x4*)(wa + (size_t)o0 * RANK + j * 4);
    __syncthreads();

#pragma unroll 4
    for (int row = 0; row < 32; ++row) {
        const f32x4 t03 = *(const f32x4*)&ts[row][0];
        const f32x4 t47 = *(const f32x4*)&ts[row][4];
        f32x4 ov;
        ov.x = dot4v(A[0], t03) + dot4v(A[1], t47);
        ov.y = dot4v(A[2], t03) + dot4v(A[3], t47);
        ov.z = dot4v(A[4], t03) + dot4v(A[5], t47);
        ov.w = dot4v(A[6], t03) + dot4v(A[7], t47);
        *(f32x4*)(out + (m0 + row) * D + o0) = ov;  // plain store
    }
}

extern "C" void kernel_launch(void* const* d_in, const int* in_sizes, int n_in,
                              void* d_out, int out_size, void* d_ws, size_t ws_size,
                              hipStream_t stream) {
    const float* h   = (const float*)d_in[0];
    const float* wa1 = (const float*)d_in[1];
    const float* wb1 = (const float*)d_in[2];
    const float* wa2 = (const float*)d_in[3];
    const float* wb2 = (const float*)d_in[4];
    const int*   ts  = (const int*)d_in[5];
    float* out = (float*)d_out;

    const int rows = in_sizes[0] / D;  // 8192

    unsigned* hdr  = (unsigned*)d_ws;
    unsigned* gcnt = (unsigned*)((char*)d_ws + WS_GCNT_OFF);
    unsigned long long* gsum = (unsigned long long*)((char*)d_ws + WS_GSUM_OFF);
    unsigned* bmax = (unsigned*)((char*)d_ws + WS_BMAX_OFF);
    float*    tbuf = (float*)((char*)d_ws + WS_T_OFF);

    hipLaunchKernelGGL(k_pass_max, dim3(256, 2), dim3(256), 0, stream,
                       wa1, wb1, wa2, wb2, gcnt, bmax);
    hipLaunchKernelGGL(k_pass_hist, dim3(256, 2), dim3(256), 0, stream,
                       wa1, wb1, wa2, wb2, bmax, gcnt, gsum);
    hipLaunchKernelGGL(k_select, dim3(1), dim3(1024), 0, stream,
                       hdr, bmax, gcnt, gsum, ts);
    hipLaunchKernelGGL(k_t, dim3(rows / 16), dim3(256), 0, stream,
                       h, wb1, wb2, hdr, tbuf);
    hipLaunchKernelGGL(k_o, dim3(4 * (rows / 32)), dim3(256), 0, stream,
                       tbuf, wa1, wa2, hdr, out);
}